// Round 1
// baseline (259.361 us; speedup 1.0000x reference)
//
#include <hip/hip_runtime.h>

typedef __attribute__((ext_vector_type(4))) float f32x4;

// ---------------------------------------------------------------------------
// Quantize x (f32, M x 128 row-major) -> fp8 e4m3fn, same linear layout.
// 8 elements per thread, u64 stores.
// ---------------------------------------------------------------------------
__global__ void quant_x_kernel(const float* __restrict__ in,
                               const float* __restrict__ scale,
                               unsigned long long* __restrict__ out, int n8) {
    int idx = blockIdx.x * blockDim.x + threadIdx.x;
    int stride = gridDim.x * blockDim.x;
    float s = scale[0];
    for (int i = idx; i < n8; i += stride) {
        float4 a = reinterpret_cast<const float4*>(in)[2 * (size_t)i];
        float4 b = reinterpret_cast<const float4*>(in)[2 * (size_t)i + 1];
        int lo = 0, hi = 0;
        lo = __builtin_amdgcn_cvt_pk_fp8_f32(a.x * s, a.y * s, lo, false);
        lo = __builtin_amdgcn_cvt_pk_fp8_f32(a.z * s, a.w * s, lo, true);
        hi = __builtin_amdgcn_cvt_pk_fp8_f32(b.x * s, b.y * s, hi, false);
        hi = __builtin_amdgcn_cvt_pk_fp8_f32(b.z * s, b.w * s, hi, true);
        out[i] = ((unsigned long long)(unsigned int)hi << 32) | (unsigned int)lo;
    }
}

// ---------------------------------------------------------------------------
// Quantize y (f32, 128 x N row-major) -> fp8 in B-fragment-major layout:
//   yp u64 index = (n/16)*256 + (k/8)*16 + (n%16), byte j within u64 = k%8
// so a GEMM B-fragment (16 cols x 8 k) is 64 lanes * 8B fully coalesced.
// One thread per (n16, k8, c) -> 8 bytes.
// ---------------------------------------------------------------------------
__global__ void quant_pack_y_kernel(const float* __restrict__ y,
                                    const float* __restrict__ scale,
                                    unsigned long long* __restrict__ yp, int N) {
    int t = blockIdx.x * blockDim.x + threadIdx.x;   // N*128/8 threads
    float s = scale[0];
    int c   = t & 15;
    int k8  = (t >> 4) & 15;
    int n16 = t >> 8;
    const float* src = y + (size_t)(k8 * 8) * N + n16 * 16 + c;
    float v[8];
#pragma unroll
    for (int j = 0; j < 8; ++j) v[j] = src[(size_t)j * N] * s;
    int lo = 0, hi = 0;
    lo = __builtin_amdgcn_cvt_pk_fp8_f32(v[0], v[1], lo, false);
    lo = __builtin_amdgcn_cvt_pk_fp8_f32(v[2], v[3], lo, true);
    hi = __builtin_amdgcn_cvt_pk_fp8_f32(v[4], v[5], hi, false);
    hi = __builtin_amdgcn_cvt_pk_fp8_f32(v[6], v[7], hi, true);
    yp[t] = ((unsigned long long)(unsigned int)hi << 32) | (unsigned int)lo;
}

// ---------------------------------------------------------------------------
// GEMM: M x 128 (fp8) @ 128 x N (fp8 packed) -> f32, scaled by 1/(sx*sy).
// 256 threads = 4 waves (2x2), each wave computes a 64x64 tile.
// No LDS: K=128 fits in registers. mfma_f32_16x16x32_fp8_fp8.
//   A frag (mf,kk): lane reads u64 at x row (m0+mf*16+lane&15), chunk kk*4+q
//   B frag (nf,kk): lane reads u64 at yp[(n0/16+nf)*256 + (kk*4+q)*16 + r]
//   C/D: col = lane&15, row = (lane>>4)*4 + reg   (dtype-independent, verified)
// ---------------------------------------------------------------------------
__global__ __launch_bounds__(256) void gemm_fp8_kernel(
    const unsigned long long* __restrict__ xq,   // [M][16] u64
    const unsigned long long* __restrict__ yp,   // packed, [N/16][16][16] u64
    const float* __restrict__ xs, const float* __restrict__ ys,
    float* __restrict__ out, int M, int N) {
    int nb   = N >> 7;                       // n-tiles of 128
    int bx   = blockIdx.x % nb;
    int by   = blockIdx.x / nb;
    int wid  = threadIdx.x >> 6;
    int lane = threadIdx.x & 63;
    int q    = lane >> 4;                    // 0..3
    int r    = lane & 15;                    // 0..15
    int m0   = by * 128 + (wid >> 1) * 64;
    int n0   = bx * 128 + (wid & 1) * 64;

    float inv = 1.0f / (xs[0] * ys[0]);

    const unsigned long long* xrow  = xq + ((size_t)(m0 + r)) * 16;        // +mf*256
    const unsigned long long* ybase = yp + ((size_t)(n0 >> 4)) * 256 + r;  // +nf*256

    f32x4 acc[4][4] = {};  // [mf][nf]

#pragma unroll
    for (int kk = 0; kk < 4; ++kk) {
        long a[4], b[4];
#pragma unroll
        for (int mf = 0; mf < 4; ++mf)
            a[mf] = (long)xrow[(size_t)mf * 256 + kk * 4 + q];
#pragma unroll
        for (int nf = 0; nf < 4; ++nf)
            b[nf] = (long)ybase[(size_t)nf * 256 + (kk * 4 + q) * 16];
#pragma unroll
        for (int mf = 0; mf < 4; ++mf)
#pragma unroll
            for (int nf = 0; nf < 4; ++nf)
                acc[mf][nf] = __builtin_amdgcn_mfma_f32_16x16x32_fp8_fp8(
                    a[mf], b[nf], acc[mf][nf], 0, 0, 0);
    }

    // Epilogue: dequant-scale and store. 16-lane x 4B contiguous segments.
#pragma unroll
    for (int mf = 0; mf < 4; ++mf) {
#pragma unroll
        for (int nf = 0; nf < 4; ++nf) {
            float* o = out + (size_t)(m0 + mf * 16 + q * 4) * N + n0 + nf * 16 + r;
#pragma unroll
            for (int i = 0; i < 4; ++i)
                o[(size_t)i * N] = acc[mf][nf][i] * inv;
        }
    }
}

extern "C" void kernel_launch(void* const* d_in, const int* in_sizes, int n_in,
                              void* d_out, int out_size, void* d_ws, size_t ws_size,
                              hipStream_t stream) {
    const float* x  = (const float*)d_in[0];   // (B,S,K) f32
    const float* y  = (const float*)d_in[1];   // (K,N)   f32
    const float* xs = (const float*)d_in[2];   // scalar
    const float* ys = (const float*)d_in[3];   // scalar
    float* out = (float*)d_out;

    const int K = 128;
    int M = in_sizes[0] / K;   // 65536
    int N = in_sizes[1] / K;   // 4096

    unsigned long long* xq = (unsigned long long*)d_ws;           // M*K bytes
    unsigned long long* yq = xq + (size_t)M * K / 8;              // K*N bytes

    int n8x = M * (K / 8);     // u64 count for x
    quant_x_kernel<<<2048, 256, 0, stream>>>(x, xs, xq, n8x);

    int n8y = N * (K / 8);     // u64 count for y (= thread count)
    quant_pack_y_kernel<<<(n8y + 255) / 256, 256, 0, stream>>>(y, ys, yq, N);

    int grid = (M / 128) * (N / 128);
    gemm_fp8_kernel<<<grid, 256, 0, stream>>>(xq, yq, xs, ys, out, M, N);
}

// Round 2
// 258.471 us; speedup vs baseline: 1.0034x; 1.0034x over previous
//
#include <hip/hip_runtime.h>

typedef __attribute__((ext_vector_type(16))) float f32x16;
typedef unsigned long long u64;

// ---------------------------------------------------------------------------
// Quantize x (f32, M x 128 row-major) -> fp8 e4m3fn in A-fragment-major pack:
//   ap u64 index = (m/32)*512 + kk*64 + lane,  lane = h*32 + r  (h=0..1, r=0..31)
//   holds x[m32*32 + r][kk*16 + h*8 .. +8]   (kk = 0..7, K=128)
// GEMM A-frag load (mf,kk) = ap[base + mf*512 + kk*64 + lane]: 512B contiguous.
// ---------------------------------------------------------------------------
__global__ void quant_x_pack(const float* __restrict__ x,
                             const float* __restrict__ scale,
                             u64* __restrict__ ap, int total) {
    int t = blockIdx.x * blockDim.x + threadIdx.x;   // total = M*16
    if (t >= total) return;
    float s = scale[0];
    int lane = t & 63;
    int kk   = (t >> 6) & 7;
    int m32  = t >> 9;
    int r = lane & 31, h = lane >> 5;
    const float* src = x + ((size_t)(m32 * 32 + r)) * 128 + kk * 16 + h * 8;
    float4 a = *reinterpret_cast<const float4*>(src);
    float4 b = *reinterpret_cast<const float4*>(src + 4);
    int lo = 0, hi = 0;
    lo = __builtin_amdgcn_cvt_pk_fp8_f32(a.x * s, a.y * s, lo, false);
    lo = __builtin_amdgcn_cvt_pk_fp8_f32(a.z * s, a.w * s, lo, true);
    hi = __builtin_amdgcn_cvt_pk_fp8_f32(b.x * s, b.y * s, hi, false);
    hi = __builtin_amdgcn_cvt_pk_fp8_f32(b.z * s, b.w * s, hi, true);
    ap[t] = ((u64)(unsigned int)hi << 32) | (unsigned int)lo;
}

// ---------------------------------------------------------------------------
// Quantize y (f32, 128 x N row-major) -> fp8 in B-fragment-major pack:
//   bp u64 index = (n/32)*512 + kk*64 + lane,  lane = h*32 + c
//   holds y[kk*16 + h*8 .. +8][n32*32 + c]
// ---------------------------------------------------------------------------
__global__ void quant_y_pack(const float* __restrict__ y,
                             const float* __restrict__ scale,
                             u64* __restrict__ bp, int N, int total) {
    int t = blockIdx.x * blockDim.x + threadIdx.x;   // total = N*16
    if (t >= total) return;
    float s = scale[0];
    int lane = t & 63;
    int kk   = (t >> 6) & 7;
    int n32  = t >> 9;
    int c = lane & 31, h = lane >> 5;
    const float* src = y + (size_t)(kk * 16 + h * 8) * N + n32 * 32 + c;
    float v[8];
#pragma unroll
    for (int j = 0; j < 8; ++j) v[j] = src[(size_t)j * N] * s;
    int lo = 0, hi = 0;
    lo = __builtin_amdgcn_cvt_pk_fp8_f32(v[0], v[1], lo, false);
    lo = __builtin_amdgcn_cvt_pk_fp8_f32(v[2], v[3], lo, true);
    hi = __builtin_amdgcn_cvt_pk_fp8_f32(v[4], v[5], hi, false);
    hi = __builtin_amdgcn_cvt_pk_fp8_f32(v[6], v[7], hi, true);
    bp[t] = ((u64)(unsigned int)hi << 32) | (unsigned int)lo;
}

// ---------------------------------------------------------------------------
// GEMM: [M x 128]fp8 @ [128 x N]fp8 -> f32 * inv.  Block = 128x128, 4 waves
// (2x2), wave tile 64x64 = 2x2 frags of mfma_f32_32x32x16_fp8_fp8, K=128 in
// registers (no LDS).
//   A/B frag: lane = h*32 + r holds 8 fp8 at [r][kk*16 + h*8..+8]  (packed ->
//             one contiguous 512B load per frag)
//   C/D: col = lane&31, row = (reg&3) + 8*(reg>>2) + 4*(lane>>5)  [m74/m101]
// Stores: each instr = 2 full 128B cache lines (32 lanes x 4B x 2 row-groups).
// XCD-bijective swizzle: blocks sharing an A-panel co-locate on one XCD's L2.
// ---------------------------------------------------------------------------
__global__ __launch_bounds__(256) void gemm_fp8_kernel(
    const u64* __restrict__ ap, const u64* __restrict__ bp,
    const float* __restrict__ xs, const float* __restrict__ ys,
    float* __restrict__ out, int M, int N, int nb) {
    int nwg = gridDim.x;             // multiple of 8
    int cpx = nwg >> 3;
    int bid = blockIdx.x;
    int swz = (bid & 7) * cpx + (bid >> 3);
    int bx  = swz % nb;
    int by  = swz / nb;

    int wid  = threadIdx.x >> 6;
    int lane = threadIdx.x & 63;
    int m0   = by * 128 + (wid >> 1) * 64;
    int n0   = bx * 128 + (wid & 1) * 64;

    float inv = 1.0f / (xs[0] * ys[0]);

    const u64* abase = ap + (size_t)(m0 >> 5) * 512 + lane;  // + mf*512 + kk*64
    const u64* bbase = bp + (size_t)(n0 >> 5) * 512 + lane;  // + nf*512 + kk*64

    f32x16 acc[2][2] = {};

#pragma unroll
    for (int kk = 0; kk < 8; ++kk) {
        long a0 = (long)abase[kk * 64];
        long a1 = (long)abase[512 + kk * 64];
        long b0 = (long)bbase[kk * 64];
        long b1 = (long)bbase[512 + kk * 64];
        acc[0][0] = __builtin_amdgcn_mfma_f32_32x32x16_fp8_fp8(a0, b0, acc[0][0], 0, 0, 0);
        acc[0][1] = __builtin_amdgcn_mfma_f32_32x32x16_fp8_fp8(a0, b1, acc[0][1], 0, 0, 0);
        acc[1][0] = __builtin_amdgcn_mfma_f32_32x32x16_fp8_fp8(a1, b0, acc[1][0], 0, 0, 0);
        acc[1][1] = __builtin_amdgcn_mfma_f32_32x32x16_fp8_fp8(a1, b1, acc[1][1], 0, 0, 0);
    }

    int col = lane & 31;
    int h4  = (lane >> 5) * 4;
#pragma unroll
    for (int mf = 0; mf < 2; ++mf) {
#pragma unroll
        for (int nf = 0; nf < 2; ++nf) {
            f32x16 c = acc[mf][nf];
            float* o = out + (size_t)(m0 + mf * 32 + h4) * N + n0 + nf * 32 + col;
#pragma unroll
            for (int rg = 0; rg < 16; ++rg) {
                int row = (rg & 3) + 8 * (rg >> 2);        // + h4 folded into o
                o[(size_t)row * N] = c[rg] * inv;
            }
        }
    }
}

extern "C" void kernel_launch(void* const* d_in, const int* in_sizes, int n_in,
                              void* d_out, int out_size, void* d_ws, size_t ws_size,
                              hipStream_t stream) {
    const float* x  = (const float*)d_in[0];   // (B,S,K) f32
    const float* y  = (const float*)d_in[1];   // (K,N)   f32
    const float* xs = (const float*)d_in[2];   // scalar
    const float* ys = (const float*)d_in[3];   // scalar
    float* out = (float*)d_out;

    const int K = 128;
    int M = in_sizes[0] / K;   // 65536
    int N = in_sizes[1] / K;   // 4096

    u64* ap = (u64*)d_ws;                      // M*K bytes
    u64* bp = ap + (size_t)M * K / 8;          // K*N bytes

    int tx = M * (K / 8);
    quant_x_pack<<<(tx + 255) / 256, 256, 0, stream>>>(x, xs, ap, tx);

    int ty = N * (K / 8);
    quant_y_pack<<<(ty + 255) / 256, 256, 0, stream>>>(y, ys, bp, N, ty);

    int nb = N / 128;
    int grid = (M / 128) * nb;                 // 16384, %8 == 0
    gemm_fp8_kernel<<<grid, 256, 0, stream>>>(ap, bp, xs, ys, out, M, N, nb);
}

// Round 3
// 197.722 us; speedup vs baseline: 1.3117x; 1.3072x over previous
//
#include <hip/hip_runtime.h>

typedef __attribute__((ext_vector_type(16))) float f32x16;
typedef unsigned long long u64;

// ---------------------------------------------------------------------------
// Quantize x (f32, M x 128 row-major) -> fp8 e4m3fn in A-fragment-major pack:
//   ap u64 index = (m/32)*512 + kk*64 + lane,  lane = h*32 + r  (h=0..1, r=0..31)
//   holds x[m32*32 + r][kk*16 + h*8 .. +8]   (kk = 0..7, K=128)
// GEMM A-frag load (mf,kk) = ap[base + mf*512 + kk*64 + lane]: 512B contiguous.
// ---------------------------------------------------------------------------
__global__ void quant_x_pack(const float* __restrict__ x,
                             const float* __restrict__ scale,
                             u64* __restrict__ ap, int total) {
    int t = blockIdx.x * blockDim.x + threadIdx.x;   // total = M*16
    if (t >= total) return;
    float s = scale[0];
    int lane = t & 63;
    int kk   = (t >> 6) & 7;
    int m32  = t >> 9;
    int r = lane & 31, h = lane >> 5;
    const float* src = x + ((size_t)(m32 * 32 + r)) * 128 + kk * 16 + h * 8;
    float4 a = *reinterpret_cast<const float4*>(src);
    float4 b = *reinterpret_cast<const float4*>(src + 4);
    int lo = 0, hi = 0;
    lo = __builtin_amdgcn_cvt_pk_fp8_f32(a.x * s, a.y * s, lo, false);
    lo = __builtin_amdgcn_cvt_pk_fp8_f32(a.z * s, a.w * s, lo, true);
    hi = __builtin_amdgcn_cvt_pk_fp8_f32(b.x * s, b.y * s, hi, false);
    hi = __builtin_amdgcn_cvt_pk_fp8_f32(b.z * s, b.w * s, hi, true);
    ap[t] = ((u64)(unsigned int)hi << 32) | (unsigned int)lo;
}

// ---------------------------------------------------------------------------
// Quantize y (f32, 128 x N row-major) -> fp8 in B-fragment-major pack:
//   bp u64 index = (n/32)*512 + kk*64 + lane,  lane = h*32 + c
//   holds y[kk*16 + h*8 .. +8][n32*32 + c]
// ---------------------------------------------------------------------------
__global__ void quant_y_pack(const float* __restrict__ y,
                             const float* __restrict__ scale,
                             u64* __restrict__ bp, int N, int total) {
    int t = blockIdx.x * blockDim.x + threadIdx.x;   // total = N*16
    if (t >= total) return;
    float s = scale[0];
    int lane = t & 63;
    int kk   = (t >> 6) & 7;
    int n32  = t >> 9;
    int c = lane & 31, h = lane >> 5;
    const float* src = y + (size_t)(kk * 16 + h * 8) * N + n32 * 32 + c;
    float v[8];
#pragma unroll
    for (int j = 0; j < 8; ++j) v[j] = src[(size_t)j * N] * s;
    int lo = 0, hi = 0;
    lo = __builtin_amdgcn_cvt_pk_fp8_f32(v[0], v[1], lo, false);
    lo = __builtin_amdgcn_cvt_pk_fp8_f32(v[2], v[3], lo, true);
    hi = __builtin_amdgcn_cvt_pk_fp8_f32(v[4], v[5], hi, false);
    hi = __builtin_amdgcn_cvt_pk_fp8_f32(v[6], v[7], hi, true);
    bp[t] = ((u64)(unsigned int)hi << 32) | (unsigned int)lo;
}

// ---------------------------------------------------------------------------
// GEMM: [M x 128]fp8 @ [128 x N]fp8 -> f32 * inv.  Block = 128x128, 4 waves
// (2x2), wave tile 64x64 = 2x2 frags of mfma_f32_32x32x16_fp8_fp8, K=128 in
// registers (no LDS).
//   A/B frag: lane = h*32 + r holds 8 fp8 at [r][kk*16 + h*8..+8]
//   C/D: col = lane&31, row = (reg&3) + 8*(reg>>2) + 4*(lane>>5)  [m74/m101]
// Output stores are NONTEMPORAL: the 1.07 GB write stream must not evict the
// A/B fp8 panels (48KB+512KB per XCD) from L2 — that eviction was re-adding
// ~0.5 GB of HBM panel re-reads (round-2 post-mortem theory).
// XCD-bijective swizzle: blocks sharing an A-panel co-locate on one XCD's L2.
// ---------------------------------------------------------------------------
__global__ __launch_bounds__(256) void gemm_fp8_kernel(
    const u64* __restrict__ ap, const u64* __restrict__ bp,
    const float* __restrict__ xs, const float* __restrict__ ys,
    float* __restrict__ out, int M, int N, int nb) {
    int nwg = gridDim.x;             // multiple of 8
    int cpx = nwg >> 3;
    int bid = blockIdx.x;
    int swz = (bid & 7) * cpx + (bid >> 3);
    int bx  = swz % nb;
    int by  = swz / nb;

    int wid  = threadIdx.x >> 6;
    int lane = threadIdx.x & 63;
    int m0   = by * 128 + (wid >> 1) * 64;
    int n0   = bx * 128 + (wid & 1) * 64;

    float inv = 1.0f / (xs[0] * ys[0]);

    const u64* abase = ap + (size_t)(m0 >> 5) * 512 + lane;  // + mf*512 + kk*64
    const u64* bbase = bp + (size_t)(n0 >> 5) * 512 + lane;  // + nf*512 + kk*64

    f32x16 acc[2][2] = {};

#pragma unroll
    for (int kk = 0; kk < 8; ++kk) {
        long a0 = (long)abase[kk * 64];
        long a1 = (long)abase[512 + kk * 64];
        long b0 = (long)bbase[kk * 64];
        long b1 = (long)bbase[512 + kk * 64];
        acc[0][0] = __builtin_amdgcn_mfma_f32_32x32x16_fp8_fp8(a0, b0, acc[0][0], 0, 0, 0);
        acc[0][1] = __builtin_amdgcn_mfma_f32_32x32x16_fp8_fp8(a0, b1, acc[0][1], 0, 0, 0);
        acc[1][0] = __builtin_amdgcn_mfma_f32_32x32x16_fp8_fp8(a1, b0, acc[1][0], 0, 0, 0);
        acc[1][1] = __builtin_amdgcn_mfma_f32_32x32x16_fp8_fp8(a1, b1, acc[1][1], 0, 0, 0);
    }

    int col = lane & 31;
    int h4  = (lane >> 5) * 4;
#pragma unroll
    for (int mf = 0; mf < 2; ++mf) {
#pragma unroll
        for (int nf = 0; nf < 2; ++nf) {
            f32x16 c = acc[mf][nf];
            float* o = out + (size_t)(m0 + mf * 32 + h4) * N + n0 + nf * 32 + col;
#pragma unroll
            for (int rg = 0; rg < 16; ++rg) {
                int row = (rg & 3) + 8 * (rg >> 2);        // + h4 folded into o
                __builtin_nontemporal_store(c[rg] * inv, o + (size_t)row * N);
            }
        }
    }
}

extern "C" void kernel_launch(void* const* d_in, const int* in_sizes, int n_in,
                              void* d_out, int out_size, void* d_ws, size_t ws_size,
                              hipStream_t stream) {
    const float* x  = (const float*)d_in[0];   // (B,S,K) f32
    const float* y  = (const float*)d_in[1];   // (K,N)   f32
    const float* xs = (const float*)d_in[2];   // scalar
    const float* ys = (const float*)d_in[3];   // scalar
    float* out = (float*)d_out;

    const int K = 128;
    int M = in_sizes[0] / K;   // 65536
    int N = in_sizes[1] / K;   // 4096

    u64* ap = (u64*)d_ws;                      // M*K bytes
    u64* bp = ap + (size_t)M * K / 8;          // K*N bytes

    int tx = M * (K / 8);
    quant_x_pack<<<(tx + 255) / 256, 256, 0, stream>>>(x, xs, ap, tx);

    int ty = N * (K / 8);
    quant_y_pack<<<(ty + 255) / 256, 256, 0, stream>>>(y, ys, bp, N, ty);

    int nb = N / 128;
    int grid = (M / 128) * nb;                 // 16384, %8 == 0
    gemm_fp8_kernel<<<grid, 256, 0, stream>>>(ap, bp, xs, ys, out, M, N, nb);
}